// Round 7
// baseline (348.335 us; speedup 1.0000x reference)
//
#include <hip/hip_runtime.h>
#include <hip/hip_bf16.h>
#include <stdint.h>

typedef unsigned short ushort_t;
typedef __attribute__((ext_vector_type(8))) short bf16x8;
typedef __attribute__((ext_vector_type(4))) float f32x4;

__device__ __forceinline__ ushort_t f2bf(float f) {
    uint32_t u = __builtin_bit_cast(uint32_t, f);
    u += 0x7FFF + ((u >> 16) & 1);   // RNE
    return (ushort_t)(u >> 16);
}
__device__ __forceinline__ float bf2f(ushort_t h) {
    return __builtin_bit_cast(float, (uint32_t)h << 16);
}

__device__ __forceinline__ f32x4 mfma16(bf16x8 a, bf16x8 b, f32x4 c) {
    return __builtin_amdgcn_mfma_f32_16x16x32_bf16(a, b, c, 0, 0, 0);
}

#define GLL(g, l) __builtin_amdgcn_global_load_lds(                              \
    (const __attribute__((address_space(1))) void*)(g),                          \
    (__attribute__((address_space(3))) void*)(l), 16, 0, 0)

#define CFENCE asm volatile("" ::: "memory")
#define BARRIER do { CFENCE; __builtin_amdgcn_s_barrier(); CFENCE; } while (0)
#define PRIO1 __builtin_amdgcn_s_setprio(1)
#define PRIO0 __builtin_amdgcn_s_setprio(0)
#define LGKM0 asm volatile("s_waitcnt lgkmcnt(0)" ::: "memory")
#define VM2 asm volatile("s_waitcnt vmcnt(2)" ::: "memory")
#define VM0 asm volatile("s_waitcnt vmcnt(0)" ::: "memory")

// ---------------- fused conversion kernel ----------------

__device__ __forceinline__ void cvt8(const float* s, ushort_t* d) {
    float4 a = ((const float4*)s)[0], b = ((const float4*)s)[1];
    union { bf16x8 v; ushort_t u[8]; } o;
    o.u[0] = f2bf(a.x); o.u[1] = f2bf(a.y); o.u[2] = f2bf(a.z); o.u[3] = f2bf(a.w);
    o.u[4] = f2bf(b.x); o.u[5] = f2bf(b.y); o.u[6] = f2bf(b.z); o.u[7] = f2bf(b.w);
    *(bf16x8*)d = o.v;
}

__global__ __launch_bounds__(256) void cvt_all(
    const float* __restrict__ x,
    const float* __restrict__ Wq, const float* __restrict__ Wk,
    const float* __restrict__ Wv, const float* __restrict__ Wo,
    const float* __restrict__ bq, const float* __restrict__ bk,
    const float* __restrict__ bv,
    ushort_t* __restrict__ xb, ushort_t* __restrict__ wqkv,
    float* __restrict__ bqkv)
{
    const int NX = 16384 * 1024 / 8;   // 2097152
    const int NW = 1024 * 1024 / 8;    // 131072
    int i = blockIdx.x * 256 + threadIdx.x;
    if (i < NX) {
        cvt8(x + (size_t)i * 8, xb + (size_t)i * 8);
    } else if (i < NX + 4 * NW) {
        int j = i - NX;
        int w = j >> 17, off = j & (NW - 1);
        const float* s = (w == 0) ? Wq : (w == 1) ? Wk : (w == 2) ? Wv : Wo;
        cvt8(s + (size_t)off * 8, wqkv + (size_t)j * 8);   // wqkv then wo, contiguous
    } else if (i < NX + 4 * NW + 384) {
        int j = i - NX - 4 * NW;       // 0..383 (bq|bk|bv, 128 units each)
        int w2 = j >> 7, off = j & 127;
        const float* s = (w2 == 0) ? bq : (w2 == 1) ? bk : bv;
        ((float4*)(bqkv + j * 8))[0] = ((const float4*)(s + off * 8))[0];
        ((float4*)(bqkv + j * 8))[1] = ((const float4*)(s + off * 8))[1];
    }
}

// ---------------- gemm7: m201-shape 256x256, BK=64, 4 phases/K-tile -------
// 8 waves (2m x 4n), per-wave C = 128x64 = acc[8][4]. 2 LDS dbufs of
// {A[2 half][128x64], B[2 half][128x64]} = 128 KiB, 3-bit XOR layout
// (row stride 128B, chunk ^= row&7 -> quarter-wave conflict-free).
// Phase = {ds_read (8 or 4 b128); 2 GLL stage; barrier; lgkm0; 16 MFMA; barrier}.
// Stage map (tile t): P1: B(t+1)h1 ; P2: A(t+1)h0 ; P3: A(t+1)h1 ;
//                     P4: B(t+2)h0 + vmcnt(2).
// Ledger: at [t,P4] outstanding = {B(t+2)h0, A(t+1)h1, A(t+1)h0, B(t+1)h1,
// B(t+1)h0} = 10 GLL; vmcnt(2) leaves B(t+2)h0, drains all of tile t+1. All
// stage targets are >=2 barriers after their slot's last read (lgkm0 before
// MFMA => reads complete before each phase's closing barrier).
// MODE 0: bf16 out, N=3072 QKV-split; MODE 1: fp32 out, N=1024.

#define STG7(P, rb, dst, kt) { _Pragma("unroll")                                 \
    for (int j = 0; j < 2; ++j) {                                                \
        int idx = j * 512 + tid; int row = idx >> 3, ch = idx & 7;               \
        GLL(P + (size_t)((rb) + row) * 1024 + (kt) * 64 + ((ch ^ (row & 7)) * 8),\
            (char*)(dst) + (size_t)idx * 16);                                    \
    } }

#define RDA(dst, base, kki) { _Pragma("unroll")                                  \
    for (int q = 0; q < 4; ++q)                                                  \
        dst[q] = *(const bf16x8*)&Ad[((base) + q) * 16 * 64 + ln * 64 + chA[kki]]; }
#define RDB(kki) { _Pragma("unroll")                                             \
    for (int q = 0; q < 4; ++q)                                                  \
        bb[q] = *(const bf16x8*)&Bd[(q * 16 + ln) * 64 + chA[kki]]; }

#define MFMA_P(mibase, areg) { _Pragma("unroll")                                 \
    for (int mi = 0; mi < 4; ++mi) _Pragma("unroll")                             \
        for (int ni = 0; ni < 4; ++ni)                                           \
            acc[(mibase) + mi][ni] =                                             \
                mfma16(areg[mi], bb[ni], acc[(mibase) + mi][ni]); }

template<int MODE>
__global__ __launch_bounds__(512, 1) void gemm7(
    const ushort_t* __restrict__ A, const ushort_t* __restrict__ B,
    const float* __restrict__ bias, void* __restrict__ outp,
    int M, int NTN)
{
    __shared__ ushort_t As[2][2][128 * 64];   // [dbuf][half], 64 KiB
    __shared__ ushort_t Bs[2][2][128 * 64];   // 64 KiB
    const int NK = 16;                        // K = 1024, BK = 64

    const int bid = blockIdx.x;
    const int nwg = gridDim.x;                // % 8 == 0
    const int q8 = nwg >> 3;
    const int swz = (bid & 7) * q8 + (bid >> 3);
    const int m0 = (swz / NTN) * 256;
    const int n0 = (swz % NTN) * 256;

    const int tid = threadIdx.x;
    const int wave = tid >> 6, lane = tid & 63;
    const int wm = wave >> 2, wn = wave & 3;  // 2M x 4N
    const int lg = lane >> 4, ln = lane & 15;
    int chA[2];
    chA[0] = ((0 * 4 + lg) ^ (ln & 7)) * 8;
    chA[1] = ((1 * 4 + lg) ^ (ln & 7)) * 8;

    f32x4 acc[8][4];
#pragma unroll
    for (int i2 = 0; i2 < 8; ++i2)
#pragma unroll
        for (int j2 = 0; j2 < 4; ++j2) acc[i2][j2] = (f32x4){0.f, 0.f, 0.f, 0.f};

    // prologue: tile 0 (4 half-tiles) + B(1)h0; vmcnt(2) -> tile0 resident
    STG7(A, m0 + 0,   &As[0][0][0], 0)
    STG7(A, m0 + 128, &As[0][1][0], 0)
    STG7(B, n0 + 0,   &Bs[0][0][0], 0)
    STG7(B, n0 + 128, &Bs[0][1][0], 0)
    STG7(B, n0 + 0,   &Bs[1][0][0], 1)
    VM2;
    BARRIER;

    bf16x8 a03[4], a47[4], bb[4];
    for (int t = 0; t < NK; ++t) {
        const int d = t & 1, o = d ^ 1;
        const ushort_t* Ad = &As[d][wm][0];
        const ushort_t* Bd = &Bs[d][wn >> 1][(wn & 1) * 64 * 64];
        const bool p1 = (t + 1 < NK), p2 = (t + 2 < NK);

        // ---- P1: a03@kk0 + b@kk0 (8 reads); stage B(t+1)h1 ----
        RDA(a03, 0, 0) RDB(0)
        if (p1) STG7(B, n0 + 128, &Bs[o][1][0], t + 1)
        BARRIER; LGKM0;
        PRIO1; MFMA_P(0, a03) PRIO0;
        BARRIER;

        // ---- P2: a47@kk0 (4 reads); stage A(t+1)h0 ----
        RDA(a47, 4, 0)
        if (p1) STG7(A, m0 + 0, &As[o][0][0], t + 1)
        BARRIER; LGKM0;
        PRIO1; MFMA_P(4, a47) PRIO0;
        BARRIER;

        // ---- P3: a03@kk1 + b@kk1 (8 reads); stage A(t+1)h1 ----
        RDA(a03, 0, 1) RDB(1)
        if (p1) STG7(A, m0 + 128, &As[o][1][0], t + 1)
        BARRIER; LGKM0;
        PRIO1; MFMA_P(0, a03) PRIO0;
        BARRIER;

        // ---- P4: a47@kk1 (4 reads); stage B(t+2)h0; counted vmcnt ----
        RDA(a47, 4, 1)
        if (p2) STG7(B, n0 + 0, &Bs[d][0][0], t + 2)
        if (p2)      { VM2; }
        else if (p1) { VM0; }
        BARRIER; LGKM0;
        PRIO1; MFMA_P(4, a47) PRIO0;
        BARRIER;
    }

    // ---- epilogue: mi,r outer / ni inner -> contiguous 128B runs per wave ----
    float bval[4];
#pragma unroll
    for (int ni = 0; ni < 4; ++ni) bval[ni] = bias[n0 + wn * 64 + ni * 16 + ln];

    if (MODE == 0) {
        ushort_t* obase = (ushort_t*)outp + (size_t)(n0 >> 10) * ((size_t)M * 1024)
                          + (n0 & 1023) + wn * 64 + ln;
#pragma unroll
        for (int mi = 0; mi < 8; ++mi) {
#pragma unroll
            for (int r = 0; r < 4; ++r) {
                int m = m0 + wm * 128 + mi * 16 + lg * 4 + r;
                ushort_t* orow = obase + (size_t)m * 1024;
#pragma unroll
                for (int ni = 0; ni < 4; ++ni)
                    orow[ni * 16] = f2bf(acc[mi][ni][r] + bval[ni]);
            }
        }
    } else {
        float* obase = (float*)outp + n0 + wn * 64 + ln;
#pragma unroll
        for (int mi = 0; mi < 8; ++mi) {
#pragma unroll
            for (int r = 0; r < 4; ++r) {
                int m = m0 + wm * 128 + mi * 16 + lg * 4 + r;
                float* orow = obase + (size_t)m * 1024;
#pragma unroll
                for (int ni = 0; ni < 4; ++ni)
                    orow[ni * 16] = acc[mi][ni][r] + bval[ni];
            }
        }
    }
}

// ---------------- attention helpers ----------------

__device__ __forceinline__ bf16x8 bias8(const float* __restrict__ b, int off) {
    float4 f0 = *(const float4*)(b + off);
    float4 f1 = *(const float4*)(b + off + 4);
    union { bf16x8 v; ushort_t u[8]; } o;
    o.u[0] = f2bf(f0.x); o.u[1] = f2bf(f0.y); o.u[2] = f2bf(f0.z); o.u[3] = f2bf(f0.w);
    o.u[4] = f2bf(f1.x); o.u[5] = f2bf(f1.y); o.u[6] = f2bf(f1.z); o.u[7] = f2bf(f1.w);
    return o.v;
}

// ---------------- fused band attention ----------------
// A 48-token band contains exactly 3 local 16-chunks AND the 3 atrous chunks
// (token 3*(16*band+i)+dil = 48*band + 3i + dil). 6 waves: w<3 local chunk w,
// w>=3 atrous dil=w-3. Per head: all waves compute 16x16 attention; local
// waves write (=) fp32 Sacc[48][64], barrier, atrous waves add (+=), barrier,
// cooperative bf16 store (guard token<4096), barrier. Bands: 86 per batch
// (85 full + 16-token tail; phantom local waves & padded atrous rows never
// stored; OOB reads land in the adjacent d_ws buffer - memory-safe).

__global__ __launch_bounds__(384) void attn_band(
    const ushort_t* __restrict__ Q, const ushort_t* __restrict__ K,
    const ushort_t* __restrict__ V,
    const float* __restrict__ bq, const float* __restrict__ bk,
    const float* __restrict__ bv, ushort_t* __restrict__ S)
{
    const int wave = threadIdx.x >> 6, lane = threadIdx.x & 63;
    const int g = lane >> 4, nn = lane & 15;
    const int bid = blockIdx.x;                 // 4 batches * 86 bands * 4 hq
    const int hq = bid & 3;
    const int t2 = bid >> 2;
    const int band = t2 % 86;
    const int b = t2 / 86;

    __shared__ float Sacc[48 * 64];             // 12 KiB
    __shared__ ushort_t vt[6][64 * 16];         // 12 KiB, vt[d][n] = V[n][d]
    __shared__ ushort_t lds_p[6][16 * 16];      // 3 KiB

    const bool is_local = (wave < 3);
    const int dil = wave - 3;
    const int tb = band * 48;                   // band-relative token base
    const size_t batch0 = (size_t)b * 4096;

    // token index (band-relative) for this wave's q/k row `i`:
    //   local: tb + wave*16 + i ; atrous: tb + 3*i + dil
    for (int hi = 0; hi < 4; ++hi) {
        const int h = hq * 4 + hi;
        const int dof = h * 64 + g * 8;

        // ---- load q/k fragments (row nn) ----
        int tok_n = is_local ? (tb + wave * 16 + nn) : (tb + 3 * nn + dil);
        bf16x8 qa0, qa1, kb0, kb1;
        if (is_local || tok_n < 4096) {
            size_t off = (batch0 + tok_n) * 1024 + dof;
            qa0 = *(const bf16x8*)(Q + off);
            qa1 = *(const bf16x8*)(Q + off + 32);
            kb0 = *(const bf16x8*)(K + off);
            kb1 = *(const bf16x8*)(K + off + 32);
        } else {
            qa0 = bias8(bq, dof); qa1 = bias8(bq, dof + 32);
            kb0 = bias8(bk, dof); kb1 = bias8(bk, dof + 32);
        }

        // ---- V transpose into per-wave LDS slice ----
#pragma unroll
        for (int it = 0; it < 2; ++it) {
            int u = it * 64 + lane;
            int n = u >> 3, cc = u & 7;
            int tok_v = is_local ? (tb + wave * 16 + n) : (tb + 3 * n + dil);
            bf16x8 vv = (is_local || tok_v < 4096)
                ? *(const bf16x8*)(V + (batch0 + tok_v) * 1024 + h * 64 + cc * 8)
                : bias8(bv, h * 64 + cc * 8);
            union { bf16x8 v; ushort_t u8[8]; } vu; vu.v = vv;
#pragma unroll
            for (int j = 0; j < 8; ++j) vt[wave][(cc * 8 + j) * 16 + n] = vu.u8[j];
        }

        // ---- QK^T + softmax ----
        f32x4 sc = {0.f, 0.f, 0.f, 0.f};
        sc = mfma16(qa0, kb0, sc);
        sc = mfma16(qa1, kb1, sc);
#pragma unroll
        for (int r = 0; r < 4; ++r) {
            float s = sc[r] * 0.125f;
            float mx = s;
#pragma unroll
            for (int off = 1; off < 16; off <<= 1) mx = fmaxf(mx, __shfl_xor(mx, off, 64));
            float e = __expf(s - mx);
            float sm = e;
#pragma unroll
            for (int off = 1; off < 16; off <<= 1) sm += __shfl_xor(sm, off, 64);
            lds_p[wave][(g * 4 + r) * 16 + nn] = f2bf(e / sm);
        }
        CFENCE;

        // ---- PV ----
        bf16x8 zero8 = {};
        bf16x8 pa = (g < 2) ? *(const bf16x8*)&lds_p[wave][nn * 16 + g * 8] : zero8;
        f32x4 o[4];
#pragma unroll
        for (int dt = 0; dt < 4; ++dt) {
            bf16x8 vb = (g < 2) ? *(const bf16x8*)&vt[wave][(dt * 16 + nn) * 16 + g * 8] : zero8;
            o[dt] = mfma16(pa, vb, (f32x4){0.f, 0.f, 0.f, 0.f});
        }

        // ---- accumulate into band buffer ----
        if (is_local) {
#pragma unroll
            for (int dt = 0; dt < 4; ++dt)
#pragma unroll
                for (int r = 0; r < 4; ++r)
                    Sacc[(wave * 16 + g * 4 + r) * 64 + dt * 16 + nn] = o[dt][r];
        }
        __syncthreads();
        if (!is_local) {
#pragma unroll
            for (int dt = 0; dt < 4; ++dt)
#pragma unroll
                for (int r = 0; r < 4; ++r)
                    Sacc[(3 * (g * 4 + r) + dil) * 64 + dt * 16 + nn] += o[dt][r];
        }
        __syncthreads();

        // ---- cooperative bf16 store: 48 rows x 64 cols ----
        {
            int row = threadIdx.x >> 3, cg = threadIdx.x & 7;
            int tok = tb + row;
            if (tok < 4096) {
                const float* src = &Sacc[row * 64 + cg * 8];
                union { bf16x8 v; ushort_t u8[8]; } ov;
#pragma unroll
                for (int j = 0; j < 8; ++j) ov.u8[j] = f2bf(src[j]);
                *(bf16x8*)(S + (batch0 + tok) * 1024 + h * 64 + cg * 8) = ov.v;
            }
        }
        __syncthreads();   // before next head overwrites Sacc
    }
}

// ---------------- launch ----------------

extern "C" void kernel_launch(void* const* d_in, const int* in_sizes, int n_in,
                              void* d_out, int out_size, void* d_ws, size_t ws_size,
                              hipStream_t stream)
{
    const float* x  = (const float*)d_in[0];
    const float* Wq = (const float*)d_in[1];
    const float* bq = (const float*)d_in[2];
    const float* Wk = (const float*)d_in[3];
    const float* bk = (const float*)d_in[4];
    const float* Wv = (const float*)d_in[5];
    const float* bv = (const float*)d_in[6];
    const float* Wo = (const float*)d_in[7];
    const float* bo = (const float*)d_in[8];
    float* out = (float*)d_out;

    const size_t NT = 16384;            // total tokens (4 * 4096)
    ushort_t* xb   = (ushort_t*)d_ws;                  // 16M bf16
    ushort_t* wqkv = xb + NT * 1024;                   // 3M bf16 (Wq|Wk|Wv rows)
    ushort_t* wo   = wqkv + 3 * 1024 * 1024;           // 1M bf16 (contiguous after wqkv)
    ushort_t* Qb   = wo + 1024 * 1024;                 // 16M bf16
    ushort_t* Kb   = Qb + NT * 1024;
    ushort_t* Vb   = Kb + NT * 1024;
    ushort_t* Sb   = Vb + NT * 1024;                   // local+atrous sum, bf16
    float*    bqkv = (float*)(Sb + NT * 1024);         // 3072 fp32

    // fused fp32 -> bf16 conversion + bias pack
    const int total_units = 2097152 + 4 * 131072 + 384;
    cvt_all<<<(total_units + 255) / 256, 256, 0, stream>>>(
        x, Wq, Wk, Wv, Wo, bq, bk, bv, xb, wqkv, bqkv);

    // fused QKV projection: (16384x1024) @ (3072x1024)^T ; grid 64*12=768 (%8==0)
    gemm7<0><<<768, 512, 0, stream>>>(xb, wqkv, bqkv, (void*)Qb, (int)NT, 12);

    // fused local+atrous attention: 4 batches * 86 bands * 4 head-quads
    attn_band<<<4 * 86 * 4, 384, 0, stream>>>(Qb, Kb, Vb, bq, bk, bv, Sb);

    // output projection: (16384x1024) @ (1024x1024)^T -> fp32 ; grid 64*4=256
    gemm7<1><<<256, 512, 0, stream>>>(Sb, wo, bo, (void*)out, (int)NT, 4);
}